// Round 1
// baseline (128.492 us; speedup 1.0000x reference)
//
#include <hip/hip_runtime.h>

// Performer causal linear attention, fp32, chunked-scan formulation.
// B=4, S=2048, D=128. Chunks: L=128 (query chunks, C=16/batch),
// KV sub-chunks Lk=32 (C32=64/batch) for prefix-state construction.

typedef float v4 __attribute__((ext_vector_type(4)));

#define BN 4
#define SN 2048
#define DN 128

// workspace layout (float offsets)
#define OFF_PHIK 0
#define OFF_PHIQ (BN * SN * DN)                       // 1048576
#define OFF_KV32 (OFF_PHIQ + BN * SN * DN)            // 2097152
#define OFF_N32  (OFF_KV32 + BN * 64 * DN * DN)       // 6291456
#define OFF_PKV  (OFF_N32 + BN * 64 * DN)             // 6324224
#define OFF_PN   (OFF_PKV + BN * 16 * DN * DN)        // 7372800
// total = 7380992 floats = 29.5 MB

// ---------------------------------------------------------------------------
// Kernel 1: phi(x) = (1/sqrt(128)) * exp(-0.5*||x||) * exp(W @ x)
// Block: 64 rows x 128 cols, 256 threads, 4x8 micro-tile, d streamed in 4x32.
// ---------------------------------------------------------------------------
__global__ __launch_bounds__(256) void phi_kernel(
    const float* __restrict__ K, const float* __restrict__ Q,
    const float* __restrict__ W, float* __restrict__ phiK,
    float* __restrict__ phiQ) {
  __shared__ float XT[32][68];   // XT[d_local][row]  (transposed, pad 68)
  __shared__ float WT[32][132];  // WT[d_local][m]    (transposed, pad 132)
  __shared__ float scl[64];

  const int tid = threadIdx.x;
  const float* X = blockIdx.y ? Q : K;
  float* out = blockIdx.y ? phiQ : phiK;
  const int row0 = blockIdx.x * 64;

  const int rg = tid >> 4;  // 16 row-groups
  const int cg = tid & 15;  // 16 col-groups
  const int r0 = rg * 4;
  const int c0 = cg * 4;    // cols c0..c0+3 and c0+64..c0+67 (split trick)

  float acc[4][8];
#pragma unroll
  for (int i = 0; i < 4; i++)
#pragma unroll
    for (int j = 0; j < 8; j++) acc[i][j] = 0.f;
  float sumsq = 0.f;  // valid for tid<64

  for (int dc = 0; dc < 4; dc++) {
    __syncthreads();
    // stage X tile transposed: 64 rows x 32 d
#pragma unroll
    for (int k = 0; k < 2; k++) {
      int j = tid + k * 256;  // 0..511
      int r = j >> 3;
      int d0 = (j & 7) * 4;
      v4 x4 = *(const v4*)&X[(size_t)(row0 + r) * 128 + dc * 32 + d0];
      XT[d0 + 0][r] = x4[0];
      XT[d0 + 1][r] = x4[1];
      XT[d0 + 2][r] = x4[2];
      XT[d0 + 3][r] = x4[3];
    }
    // stage W tile transposed: 128 m x 32 d
#pragma unroll
    for (int k = 0; k < 4; k++) {
      int j = tid + k * 256;  // 0..1023
      int m = j >> 3;
      int d0 = (j & 7) * 4;
      v4 w4 = *(const v4*)&W[(size_t)m * 128 + dc * 32 + d0];
      WT[d0 + 0][m] = w4[0];
      WT[d0 + 1][m] = w4[1];
      WT[d0 + 2][m] = w4[2];
      WT[d0 + 3][m] = w4[3];
    }
    __syncthreads();
    if (tid < 64) {
#pragma unroll
      for (int dd = 0; dd < 32; dd++) {
        float v = XT[dd][tid];
        sumsq += v * v;
      }
    }
#pragma unroll
    for (int d4 = 0; d4 < 8; d4++) {
      v4 xv[4], wv0[4], wv1[4];
#pragma unroll
      for (int k = 0; k < 4; k++) {
        int d = d4 * 4 + k;
        xv[k] = *(const v4*)&XT[d][r0];
        wv0[k] = *(const v4*)&WT[d][c0];
        wv1[k] = *(const v4*)&WT[d][c0 + 64];
      }
#pragma unroll
      for (int k = 0; k < 4; k++)
#pragma unroll
        for (int i = 0; i < 4; i++) {
          float x = xv[k][i];
#pragma unroll
          for (int j = 0; j < 4; j++) {
            acc[i][j] += x * wv0[k][j];
            acc[i][j + 4] += x * wv1[k][j];
          }
        }
    }
  }
  if (tid < 64) scl[tid] = 0.08838834764831845f * __expf(-0.5f * sqrtf(sumsq));
  __syncthreads();
#pragma unroll
  for (int i = 0; i < 4; i++) {
    float s = scl[r0 + i];
    v4 o0, o1;
#pragma unroll
    for (int j = 0; j < 4; j++) {
      o0[j] = s * __expf(acc[i][j]);
      o1[j] = s * __expf(acc[i][j + 4]);
    }
    *(v4*)&out[(size_t)(row0 + r0 + i) * 128 + c0] = o0;
    *(v4*)&out[(size_t)(row0 + r0 + i) * 128 + c0 + 64] = o1;
  }
}

// ---------------------------------------------------------------------------
// Kernel 2: per-32-row sub-chunk sums: KV32[d][e] = sum_s phiK[s][d]*V[s][e],
// N32[d] = sum_s phiK[s][d].  Grid: B*64 blocks, 256 thr, 8x8 micro-tile.
// ---------------------------------------------------------------------------
__global__ __launch_bounds__(256) void kv_kernel(
    const float* __restrict__ phiK, const float* __restrict__ V,
    float* __restrict__ KV32, float* __restrict__ N32) {
  __shared__ float Ks[32][128];
  __shared__ float Vs[32][128];
  const int tid = threadIdx.x;
  const int b = blockIdx.x >> 6;
  const int c32 = blockIdx.x & 63;
  const int srow0 = b * 2048 + c32 * 32;

#pragma unroll
  for (int k = 0; k < 4; k++) {
    int j = tid + k * 256;  // 0..1023
    int r = j >> 5;
    int c4 = (j & 31) * 4;
    *(v4*)&Ks[r][c4] = *(const v4*)&phiK[(size_t)(srow0 + r) * 128 + c4];
    *(v4*)&Vs[r][c4] = *(const v4*)&V[(size_t)(srow0 + r) * 128 + c4];
  }
  __syncthreads();

  const int d0 = (tid >> 4) * 8;
  const int e0 = (tid & 15) * 4;  // cols e0..e0+3 and e0+64..e0+67
  float acc[8][8];
#pragma unroll
  for (int i = 0; i < 8; i++)
#pragma unroll
    for (int j = 0; j < 8; j++) acc[i][j] = 0.f;

#pragma unroll 4
  for (int s = 0; s < 32; s++) {
    v4 a0 = *(const v4*)&Ks[s][d0];
    v4 a1 = *(const v4*)&Ks[s][d0 + 4];
    v4 b0 = *(const v4*)&Vs[s][e0];
    v4 b1 = *(const v4*)&Vs[s][e0 + 64];
#pragma unroll
    for (int i = 0; i < 4; i++)
#pragma unroll
      for (int j = 0; j < 4; j++) {
        acc[i][j] += a0[i] * b0[j];
        acc[i][j + 4] += a0[i] * b1[j];
        acc[i + 4][j] += a1[i] * b0[j];
        acc[i + 4][j + 4] += a1[i] * b1[j];
      }
  }

  if (tid < 128) {
    float ns = 0.f;
#pragma unroll
    for (int s = 0; s < 32; s++) ns += Ks[s][tid];
    N32[(size_t)(b * 64 + c32) * 128 + tid] = ns;
  }

  const size_t base = (size_t)(b * 64 + c32) * (128 * 128);
#pragma unroll
  for (int i = 0; i < 8; i++) {
    v4 o0, o1;
#pragma unroll
    for (int j = 0; j < 4; j++) {
      o0[j] = acc[i][j];
      o1[j] = acc[i][j + 4];
    }
    *(v4*)&KV32[base + (size_t)(d0 + i) * 128 + e0] = o0;
    *(v4*)&KV32[base + (size_t)(d0 + i) * 128 + e0 + 64] = o1;
  }
}

// ---------------------------------------------------------------------------
// Kernel 3: exclusive prefix over 64 sub-chunks, emitted at every 4th boundary
// (= 128-step chunk starts).  Blocks 0..511: KV rows (b,d); 512..515: N.
// ---------------------------------------------------------------------------
__global__ __launch_bounds__(128) void prefix_kernel(
    const float* __restrict__ KV32, const float* __restrict__ N32,
    float* __restrict__ PKV, float* __restrict__ PN) {
  const int tid = threadIdx.x;
  const int bid = blockIdx.x;
  if (bid < 512) {
    const int b = bid >> 7;
    const int d = bid & 127;
    const float* src = KV32 + ((size_t)b * 64 * 128 + d) * 128 + tid;
    float* dst = PKV + ((size_t)b * 16 * 128 + d) * 128 + tid;
    float acc = 0.f;
#pragma unroll
    for (int c = 0; c < 64; c++) {
      if ((c & 3) == 0) dst[(size_t)(c >> 2) * 16384] = acc;
      acc += src[(size_t)c * 16384];
    }
  } else {
    const int b = bid - 512;
    float acc = 0.f;
#pragma unroll
    for (int c = 0; c < 64; c++) {
      if ((c & 3) == 0) PN[(size_t)(b * 16 + (c >> 2)) * 128 + tid] = acc;
      acc += N32[(size_t)(b * 64 + c) * 128 + tid];
    }
  }
}

// ---------------------------------------------------------------------------
// Kernel 4: outputs.  Block = (b, chunk c, strip p of 32 t-rows).
// P = phiQ_strip @ phiK_chunk^T (causal-masked), out = P@V + phiQ@M_prefix,
// denom = rowsum(P) + phiQ . N_prefix.
// ---------------------------------------------------------------------------
__global__ __launch_bounds__(256) void out_kernel(
    const float* __restrict__ phiK, const float* __restrict__ phiQ,
    const float* __restrict__ V, const float* __restrict__ PKV,
    const float* __restrict__ PN, float* __restrict__ out) {
  __shared__ float Qt[128][36];   // Qt[d][t]   (transposed Q strip)
  __shared__ float KB[32 * 132];  // phase1: KT[d_local][s]; phase2: rows[k][e]
  __shared__ float Pt[128][36];   // Pt[s][t]
  __shared__ float Ns[128];
  __shared__ float rsum[32];

  const int tid = threadIdx.x;
  const int id = blockIdx.x;
  const int b = id >> 6;
  const int c = (id >> 2) & 15;
  const int p = id & 3;
  const int qrow0 = b * 2048 + c * 128 + p * 32;
  const int krow0 = b * 2048 + c * 128;
  const int smax = (p + 1) * 32;

  // stage Qt (transposed) + Ns
#pragma unroll
  for (int k = 0; k < 4; k++) {
    int j = tid + k * 256;  // 0..1023
    int t = j >> 5;
    int d0 = (j & 31) * 4;
    v4 q = *(const v4*)&phiQ[(size_t)(qrow0 + t) * 128 + d0];
    Qt[d0 + 0][t] = q[0];
    Qt[d0 + 1][t] = q[1];
    Qt[d0 + 2][t] = q[2];
    Qt[d0 + 3][t] = q[3];
  }
  if (tid < 128) Ns[tid] = PN[(size_t)(b * 16 + c) * 128 + tid];

  const int t0 = (tid >> 5) * 4;  // 0..28
  const int s0 = (tid & 31) * 4;  // 0..124
  float acc[4][4] = {{0.f}};

  // ---- phase 1: P = Q @ K^T, d streamed in 4 chunks of 32 ----
  for (int dc = 0; dc < 4; dc++) {
    __syncthreads();
    for (int j = tid; j < smax * 8; j += 256) {
      int s = j >> 3;
      int d0 = (j & 7) * 4;
      v4 kk4 = *(const v4*)&phiK[(size_t)(krow0 + s) * 128 + dc * 32 + d0];
      KB[(d0 + 0) * 132 + s] = kk4[0];
      KB[(d0 + 1) * 132 + s] = kk4[1];
      KB[(d0 + 2) * 132 + s] = kk4[2];
      KB[(d0 + 3) * 132 + s] = kk4[3];
    }
    __syncthreads();
    if (s0 < smax) {
#pragma unroll
      for (int d4 = 0; d4 < 8; d4++) {
        v4 qv[4], kv[4];
#pragma unroll
        for (int k = 0; k < 4; k++) {
          qv[k] = *(const v4*)&Qt[dc * 32 + d4 * 4 + k][t0];
          kv[k] = *(const v4*)&KB[(d4 * 4 + k) * 132 + s0];
        }
#pragma unroll
        for (int k = 0; k < 4; k++)
#pragma unroll
          for (int i = 0; i < 4; i++)
#pragma unroll
            for (int j = 0; j < 4; j++) acc[i][j] += qv[k][i] * kv[k][j];
      }
    }
  }
  // causal mask + write Pt (transposed)
  if (s0 < smax) {
#pragma unroll
    for (int j = 0; j < 4; j++) {
      v4 pv;
#pragma unroll
      for (int i = 0; i < 4; i++)
        pv[i] = (s0 + j <= p * 32 + t0 + i) ? acc[i][j] : 0.f;
      *(v4*)&Pt[s0 + j][t0] = pv;
    }
  }
  __syncthreads();

  // ---- denominators ----
  {
    const int t = tid >> 3;
    const int p8 = tid & 7;
    float rs = 0.f;
    for (int s = p8; s < smax; s += 8) rs += Pt[s][t];
#pragma unroll
    for (int d = p8; d < 128; d += 8) rs += Qt[d][t] * Ns[d];
    rs += __shfl_down(rs, 4, 8);
    rs += __shfl_down(rs, 2, 8);
    rs += __shfl_down(rs, 1, 8);
    if (p8 == 0) rsum[t] = rs;
  }

  // ---- phase 2: out = P@V + Q@M ----
  const int e0 = (tid & 31) * 4;
  float acc2[4][4] = {{0.f}};
  for (int st = 0; st <= p; st++) {
    __syncthreads();
#pragma unroll
    for (int k = 0; k < 4; k++) {
      int j = tid + k * 256;
      int r = j >> 5;
      int c4 = (j & 31) * 4;
      *(v4*)&KB[r * 132 + c4] =
          *(const v4*)&V[(size_t)(krow0 + st * 32 + r) * 128 + c4];
    }
    __syncthreads();
#pragma unroll 4
    for (int kk = 0; kk < 32; kk++) {
      v4 pv = *(const v4*)&Pt[st * 32 + kk][t0];
      v4 vv = *(const v4*)&KB[kk * 132 + e0];
#pragma unroll
      for (int i = 0; i < 4; i++)
#pragma unroll
        for (int j = 0; j < 4; j++) acc2[i][j] += pv[i] * vv[j];
    }
  }
  for (int mt = 0; mt < 4; mt++) {
    __syncthreads();
#pragma unroll
    for (int k = 0; k < 4; k++) {
      int j = tid + k * 256;
      int r = j >> 5;
      int c4 = (j & 31) * 4;
      *(v4*)&KB[r * 132 + c4] = *(const v4*)&PKV[((size_t)(b * 16 + c) * 128 +
                                                  mt * 32 + r) * 128 + c4];
    }
    __syncthreads();
#pragma unroll 4
    for (int kk = 0; kk < 32; kk++) {
      v4 qv = *(const v4*)&Qt[mt * 32 + kk][t0];
      v4 mv = *(const v4*)&KB[kk * 132 + e0];
#pragma unroll
      for (int i = 0; i < 4; i++)
#pragma unroll
        for (int j = 0; j < 4; j++) acc2[i][j] += qv[i] * mv[j];
    }
  }

  // ---- epilogue ----
#pragma unroll
  for (int i = 0; i < 4; i++) {
    float r = rsum[t0 + i];
    float den = r + (r > 0.f ? 1e-6f : (r < 0.f ? -1e-6f : 0.f));
    float inv = 1.f / den;
    v4 o;
#pragma unroll
    for (int j = 0; j < 4; j++) o[j] = acc2[i][j] * inv;
    *(v4*)&out[(size_t)(qrow0 + t0 + i) * 128 + e0] = o;
  }
}

// ---------------------------------------------------------------------------
extern "C" void kernel_launch(void* const* d_in, const int* in_sizes, int n_in,
                              void* d_out, int out_size, void* d_ws,
                              size_t ws_size, hipStream_t stream) {
  (void)in_sizes;
  (void)n_in;
  (void)out_size;
  (void)ws_size;
  const float* K = (const float*)d_in[0];
  const float* Q = (const float*)d_in[1];
  const float* V = (const float*)d_in[2];
  const float* W = (const float*)d_in[6];
  float* out = (float*)d_out;
  float* ws = (float*)d_ws;

  float* phiK = ws + OFF_PHIK;
  float* phiQ = ws + OFF_PHIQ;
  float* KV32 = ws + OFF_KV32;
  float* N32 = ws + OFF_N32;
  float* PKV = ws + OFF_PKV;
  float* PN = ws + OFF_PN;

  phi_kernel<<<dim3(128, 2), 256, 0, stream>>>(K, Q, W, phiK, phiQ);
  kv_kernel<<<256, 256, 0, stream>>>(phiK, V, KV32, N32);
  prefix_kernel<<<516, 128, 0, stream>>>(KV32, N32, PKV, PN);
  out_kernel<<<256, 256, 0, stream>>>(phiK, phiQ, V, PKV, PN, out);
}

// Round 2
// 105.651 us; speedup vs baseline: 1.2162x; 1.2162x over previous
//
#include <hip/hip_runtime.h>

// Performer causal linear attention, chunked-scan, bf16-MFMA formulation.
// B=4, S=2048, D=128.  Chunks L=32 (64 per batch).
//   phi:    fp32 GEMM (W@x) + exp, output bf16 phiK/phiQ
//   kv:     per-chunk KVT[e][d] = sum_s V[s][e]*phiK[s][d]  (fp32, M^T layout)
//   prefix: exclusive scan over 64 chunks -> bf16 PMb (M^T) + fp32 PN
//   out:    per-chunk MFMA: P=QK^T (masked) ; out = P@V + Q@M ; denom fp32
typedef float v4 __attribute__((ext_vector_type(4)));
typedef short s8v __attribute__((ext_vector_type(8)));   // bf16x8 fragment
typedef float f4v __attribute__((ext_vector_type(4)));   // mfma C/D
typedef unsigned short u16;
typedef u16 us4 __attribute__((ext_vector_type(4)));
typedef u16 us8 __attribute__((ext_vector_type(8)));

#define BN 4
#define SN 2048
#define DN 128

// workspace layout (float units)
#define OFF_PHIKB 0                      // bf16 [B*S*D]   -> 524288 floats
#define OFF_PHIQB 524288                 // bf16 [B*S*D]
#define OFF_KVT   1048576                // fp32 [B*64][128][128] (M^T chunks)
#define OFF_N32   5242880                // fp32 [B*64][128]
#define OFF_PMB   5275648                // bf16 [B*64][128][128] prefix M^T
#define OFF_PN    7372800                // fp32 [B*64][128] prefix N

__device__ inline u16 f2bf(float f) {
  union { float f; unsigned u; } v; v.f = f;
  unsigned r = v.u + 0x7fffu + ((v.u >> 16) & 1u);
  return (u16)(r >> 16);
}
__device__ inline float bf2f(u16 h) {
  union { unsigned u; float f; } v; v.u = ((unsigned)h) << 16; return v.f;
}

// ---------------------------------------------------------------------------
// Kernel 1: phi(x) = (1/sqrt(128))*exp(-0.5*||x||)*exp(W@x), bf16 output.
// ---------------------------------------------------------------------------
__global__ __launch_bounds__(256) void phi_kernel(
    const float* __restrict__ K, const float* __restrict__ Q,
    const float* __restrict__ W, u16* __restrict__ phiKb,
    u16* __restrict__ phiQb) {
  __shared__ float XT[32][68];
  __shared__ float WT[32][132];
  __shared__ float scl[64];

  const int tid = threadIdx.x;
  const float* X = blockIdx.y ? Q : K;
  u16* out = blockIdx.y ? phiQb : phiKb;
  const int row0 = blockIdx.x * 64;

  const int r0 = (tid >> 4) * 4;
  const int c0 = (tid & 15) * 4;

  float acc[4][8];
#pragma unroll
  for (int i = 0; i < 4; i++)
#pragma unroll
    for (int j = 0; j < 8; j++) acc[i][j] = 0.f;
  float sumsq = 0.f;

  for (int dc = 0; dc < 4; dc++) {
    __syncthreads();
#pragma unroll
    for (int k = 0; k < 2; k++) {
      int j = tid + k * 256;
      int r = j >> 3;
      int d0 = (j & 7) * 4;
      v4 x4 = *(const v4*)&X[(size_t)(row0 + r) * 128 + dc * 32 + d0];
      XT[d0 + 0][r] = x4[0]; XT[d0 + 1][r] = x4[1];
      XT[d0 + 2][r] = x4[2]; XT[d0 + 3][r] = x4[3];
    }
#pragma unroll
    for (int k = 0; k < 4; k++) {
      int j = tid + k * 256;
      int m = j >> 3;
      int d0 = (j & 7) * 4;
      v4 w4 = *(const v4*)&W[(size_t)m * 128 + dc * 32 + d0];
      WT[d0 + 0][m] = w4[0]; WT[d0 + 1][m] = w4[1];
      WT[d0 + 2][m] = w4[2]; WT[d0 + 3][m] = w4[3];
    }
    __syncthreads();
    if (tid < 64) {
#pragma unroll
      for (int dd = 0; dd < 32; dd++) { float v = XT[dd][tid]; sumsq += v * v; }
    }
#pragma unroll
    for (int d4 = 0; d4 < 8; d4++) {
      v4 xv[4], wv0[4], wv1[4];
#pragma unroll
      for (int k = 0; k < 4; k++) {
        int d = d4 * 4 + k;
        xv[k] = *(const v4*)&XT[d][r0];
        wv0[k] = *(const v4*)&WT[d][c0];
        wv1[k] = *(const v4*)&WT[d][c0 + 64];
      }
#pragma unroll
      for (int k = 0; k < 4; k++)
#pragma unroll
        for (int i = 0; i < 4; i++) {
          float x = xv[k][i];
#pragma unroll
          for (int j = 0; j < 4; j++) {
            acc[i][j] += x * wv0[k][j];
            acc[i][j + 4] += x * wv1[k][j];
          }
        }
    }
  }
  if (tid < 64) scl[tid] = 0.08838834764831845f * __expf(-0.5f * sqrtf(sumsq));
  __syncthreads();
#pragma unroll
  for (int i = 0; i < 4; i++) {
    float s = scl[r0 + i];
    us4 o0, o1;
#pragma unroll
    for (int j = 0; j < 4; j++) {
      o0[j] = f2bf(s * __expf(acc[i][j]));
      o1[j] = f2bf(s * __expf(acc[i][j + 4]));
    }
    *(us4*)&out[(size_t)(row0 + r0 + i) * 128 + c0] = o0;
    *(us4*)&out[(size_t)(row0 + r0 + i) * 128 + c0 + 64] = o1;
  }
}

// ---------------------------------------------------------------------------
// Kernel 2: per-chunk KVT[e][d] = sum_s V[s][e]*phiK[s][d] (fp32, M^T),
// N32[d] = sum_s phiK[s][d].  256 blocks (b,c), 256 thr, 8x8 micro-tile.
// ---------------------------------------------------------------------------
__global__ __launch_bounds__(256) void kv_kernel(
    const u16* __restrict__ phiKb, const float* __restrict__ V,
    float* __restrict__ KVT, float* __restrict__ N32) {
  __shared__ float Ks[32][128];
  __shared__ float Vs[32][128];
  const int tid = threadIdx.x;
  const int b = blockIdx.x >> 6;
  const int c = blockIdx.x & 63;
  const int srow0 = b * 2048 + c * 32;

#pragma unroll
  for (int k = 0; k < 2; k++) {  // phiK bf16 -> fp32 LDS
    int j = tid + k * 256;       // 0..511
    int s = j >> 4;
    int d8 = (j & 15) * 8;
    us8 kk = *(const us8*)&phiKb[(size_t)(srow0 + s) * 128 + d8];
#pragma unroll
    for (int i = 0; i < 8; i++) Ks[s][d8 + i] = bf2f(kk[i]);
  }
#pragma unroll
  for (int k = 0; k < 4; k++) {  // V fp32
    int j = tid + k * 256;
    int s = j >> 5;
    int e4 = (j & 31) * 4;
    *(v4*)&Vs[s][e4] = *(const v4*)&V[(size_t)(srow0 + s) * 128 + e4];
  }
  __syncthreads();

  const int e0 = (tid >> 4) * 8;  // rows = e
  const int d0 = (tid & 15) * 4;  // cols = d (split +64)
  float acc[8][8];
#pragma unroll
  for (int i = 0; i < 8; i++)
#pragma unroll
    for (int j = 0; j < 8; j++) acc[i][j] = 0.f;

#pragma unroll 4
  for (int s = 0; s < 32; s++) {
    v4 a0 = *(const v4*)&Vs[s][e0];
    v4 a1 = *(const v4*)&Vs[s][e0 + 4];
    v4 b0 = *(const v4*)&Ks[s][d0];
    v4 b1 = *(const v4*)&Ks[s][d0 + 64];
#pragma unroll
    for (int i = 0; i < 4; i++)
#pragma unroll
      for (int j = 0; j < 4; j++) {
        acc[i][j] += a0[i] * b0[j];
        acc[i][j + 4] += a0[i] * b1[j];
        acc[i + 4][j] += a1[i] * b0[j];
        acc[i + 4][j + 4] += a1[i] * b1[j];
      }
  }

  if (tid < 128) {
    float ns = 0.f;
#pragma unroll
    for (int s = 0; s < 32; s++) ns += Ks[s][tid];
    N32[(size_t)(b * 64 + c) * 128 + tid] = ns;
  }

  const size_t base = (size_t)(b * 64 + c) * (128 * 128);
#pragma unroll
  for (int i = 0; i < 8; i++) {
    v4 o0, o1;
#pragma unroll
    for (int j = 0; j < 4; j++) { o0[j] = acc[i][j]; o1[j] = acc[i][j + 4]; }
    *(v4*)&KVT[base + (size_t)(e0 + i) * 128 + d0] = o0;
    *(v4*)&KVT[base + (size_t)(e0 + i) * 128 + d0 + 64] = o1;
  }
}

// ---------------------------------------------------------------------------
// Kernel 3: exclusive prefix over 64 chunks; emit bf16 M^T state per chunk.
// Blocks 0..511: (b,e) rows; 512..515: N.
// ---------------------------------------------------------------------------
__global__ __launch_bounds__(128) void prefix_kernel(
    const float* __restrict__ KVT, const float* __restrict__ N32,
    u16* __restrict__ PMb, float* __restrict__ PN) {
  const int tid = threadIdx.x;
  const int bid = blockIdx.x;
  if (bid < 512) {
    const int b = bid >> 7;
    const int e = bid & 127;
    const float* src = KVT + ((size_t)(b * 64) * 128 + e) * 128 + tid;
    u16* dst = PMb + ((size_t)(b * 64) * 128 + e) * 128 + tid;
    float acc = 0.f;
#pragma unroll 8
    for (int c = 0; c < 64; c++) {
      dst[(size_t)c * 16384] = f2bf(acc);
      acc += src[(size_t)c * 16384];
    }
  } else {
    const int b = bid - 512;
    float acc = 0.f;
#pragma unroll 8
    for (int c = 0; c < 64; c++) {
      PN[(size_t)(b * 64 + c) * 128 + tid] = acc;
      acc += N32[(size_t)(b * 64 + c) * 128 + tid];
    }
  }
}

// ---------------------------------------------------------------------------
// Kernel 4: per-chunk outputs via MFMA 16x16x32 bf16.
// Block = (b, c): 32 queries x 128 e.  4 waves.
//   phase1: P[32][32] = Q.K^T (K=128), causal mask, bf16 -> Ps (A-layout)
//   denom:  rs[t] = rowsum(P) + Q[t,:].PN  (fp32 vector)
//   phase2: out[32][128] = P@V + Q@M  (wave = 32-col e-slice)
// Fragment maps (m89/m120-verified): A[m=lane&15][k=quad*8+j] k-contig;
// B[k=quad*8+j][n=lane&15]; C/D col=lane&15,row=quad*4+reg.
// ---------------------------------------------------------------------------
__global__ __launch_bounds__(256) void out_kernel(
    const u16* __restrict__ phiKb, const u16* __restrict__ phiQb,
    const float* __restrict__ V, const u16* __restrict__ PMb,
    const float* __restrict__ PN, float* __restrict__ out) {
  // Qs/Ks rows padded to 136 (272B = 17*16: 16B-aligned, 2-way banks = free)
  __shared__ __align__(16) u16 Qs[32][136];
  __shared__ __align__(16) u16 Ms[128][136];   // M^T: Ms[e][d]
  __shared__ __align__(16) u16 KsVt[128 * 40]; // phase1 Ks[32][136] / phase2 Vt[128][40]
  __shared__ __align__(16) u16 Ps[32][40];     // masked P, A-friendly [t][s]
  __shared__ float Ns[128];
  __shared__ float rs[32];

  const int tid = threadIdx.x;
  const int b = blockIdx.x >> 6;
  const int c = blockIdx.x & 63;
  const int srow0 = b * 2048 + c * 32;
  const int wave = tid >> 6;
  const int lane = tid & 63;
  const int q = lane >> 4;
  const int ln = lane & 15;

  // ---- stage Qs, Ks, Ms, Ns ----
#pragma unroll
  for (int k = 0; k < 2; k++) {
    int j = tid + k * 256;   // 0..511 : 32 rows x 16 us8
    int t = j >> 4;
    int d8 = (j & 15) * 8;
    *(us8*)&Qs[t][d8] = *(const us8*)&phiQb[(size_t)(srow0 + t) * 128 + d8];
    *(us8*)&KsVt[t * 136 + d8] =
        *(const us8*)&phiKb[(size_t)(srow0 + t) * 128 + d8];
  }
#pragma unroll
  for (int k = 0; k < 8; k++) {
    int j = tid + k * 256;   // 0..2047 : 128 rows x 16 us8
    int e = j >> 4;
    int d8 = (j & 15) * 8;
    *(us8*)&Ms[e][d8] =
        *(const us8*)&PMb[((size_t)(b * 64 + c) * 128 + e) * 128 + d8];
  }
  if (tid < 128) Ns[tid] = PN[(size_t)(b * 64 + c) * 128 + tid];
  __syncthreads();

  // ---- phase 1: P tiles (wave w -> tile (w>>1, w&1)) ----
  {
    const int tr = wave >> 1, tc = wave & 1;
    f4v acc = {0.f, 0.f, 0.f, 0.f};
#pragma unroll
    for (int ks = 0; ks < 4; ks++) {
      s8v a = *(const s8v*)&Qs[tr * 16 + ln][ks * 32 + q * 8];
      s8v bb = *(const s8v*)&KsVt[(tc * 16 + ln) * 136 + ks * 32 + q * 8];
      acc = __builtin_amdgcn_mfma_f32_16x16x32_bf16(a, bb, acc, 0, 0, 0);
    }
    const int s_g = tc * 16 + ln;
#pragma unroll
    for (int r = 0; r < 4; r++) {
      int t_g = tr * 16 + q * 4 + r;
      Ps[t_g][s_g] = f2bf(s_g <= t_g ? acc[r] : 0.f);
    }
  }
  __syncthreads();

  // ---- stage Vt (overwrites Ks) + denominators ----
#pragma unroll
  for (int k = 0; k < 4; k++) {
    int j = tid + k * 256;   // 0..1023
    int s = j & 31;
    int e4 = (j >> 5) * 4;
    v4 vv = *(const v4*)&V[(size_t)(srow0 + s) * 128 + e4];
#pragma unroll
    for (int i = 0; i < 4; i++) KsVt[(e4 + i) * 40 + s] = f2bf(vv[i]);
  }
  {
    const int t = tid >> 3;
    const int p8 = tid & 7;
    float rsl = 0.f;
#pragma unroll
    for (int s = p8; s < 32; s += 8) rsl += bf2f(Ps[t][s]);
#pragma unroll
    for (int d = p8; d < 128; d += 8) rsl += bf2f(Qs[t][d]) * Ns[d];
    rsl += __shfl_down(rsl, 4, 8);
    rsl += __shfl_down(rsl, 2, 8);
    rsl += __shfl_down(rsl, 1, 8);
    if (p8 == 0) rs[t] = rsl;
  }
  __syncthreads();

  // ---- phase 2: out slice (wave -> e0 = wave*32), 2x2 tiles ----
  const int e0 = wave * 32;
  f4v acc2[2][2];
#pragma unroll
  for (int i = 0; i < 2; i++)
#pragma unroll
    for (int j = 0; j < 2; j++) acc2[i][j] = (f4v){0.f, 0.f, 0.f, 0.f};

#pragma unroll
  for (int tr2 = 0; tr2 < 2; tr2++) {
    s8v a_p = *(const s8v*)&Ps[tr2 * 16 + ln][q * 8];
#pragma unroll
    for (int tc2 = 0; tc2 < 2; tc2++) {
      s8v b_v = *(const s8v*)&KsVt[(e0 + tc2 * 16 + ln) * 40 + q * 8];
      acc2[tr2][tc2] =
          __builtin_amdgcn_mfma_f32_16x16x32_bf16(a_p, b_v, acc2[tr2][tc2], 0, 0, 0);
    }
  }
#pragma unroll
  for (int ks = 0; ks < 4; ks++) {
#pragma unroll
    for (int tr2 = 0; tr2 < 2; tr2++) {
      s8v a_q = *(const s8v*)&Qs[tr2 * 16 + ln][ks * 32 + q * 8];
#pragma unroll
      for (int tc2 = 0; tc2 < 2; tc2++) {
        s8v b_m = *(const s8v*)&Ms[e0 + tc2 * 16 + ln][ks * 32 + q * 8];
        acc2[tr2][tc2] =
            __builtin_amdgcn_mfma_f32_16x16x32_bf16(a_q, b_m, acc2[tr2][tc2], 0, 0, 0);
      }
    }
  }

  // ---- epilogue ----
#pragma unroll
  for (int tr2 = 0; tr2 < 2; tr2++) {
#pragma unroll
    for (int r = 0; r < 4; r++) {
      int t_g = tr2 * 16 + q * 4 + r;
      float rv = rs[t_g];
      float den = rv + (rv > 0.f ? 1e-6f : (rv < 0.f ? -1e-6f : 0.f));
      float inv = 1.f / den;
#pragma unroll
      for (int tc2 = 0; tc2 < 2; tc2++) {
        int e_g = e0 + tc2 * 16 + ln;
        out[(size_t)(srow0 + t_g) * 128 + e_g] = acc2[tr2][tc2][r] * inv;
      }
    }
  }
}

// ---------------------------------------------------------------------------
extern "C" void kernel_launch(void* const* d_in, const int* in_sizes, int n_in,
                              void* d_out, int out_size, void* d_ws,
                              size_t ws_size, hipStream_t stream) {
  (void)in_sizes; (void)n_in; (void)out_size; (void)ws_size;
  const float* K = (const float*)d_in[0];
  const float* Q = (const float*)d_in[1];
  const float* V = (const float*)d_in[2];
  const float* W = (const float*)d_in[6];
  float* out = (float*)d_out;
  float* ws = (float*)d_ws;

  u16* phiKb = (u16*)(ws + OFF_PHIKB);
  u16* phiQb = (u16*)(ws + OFF_PHIQB);
  float* KVT = ws + OFF_KVT;
  float* N32 = ws + OFF_N32;
  u16* PMb = (u16*)(ws + OFF_PMB);
  float* PN = ws + OFF_PN;

  phi_kernel<<<dim3(128, 2), 256, 0, stream>>>(K, Q, W, phiKb, phiQb);
  kv_kernel<<<256, 256, 0, stream>>>(phiKb, V, KVT, N32);
  prefix_kernel<<<516, 128, 0, stream>>>(KVT, N32, PMb, PN);
  out_kernel<<<256, 256, 0, stream>>>(phiKb, phiQb, V, PMb, PN, out);
}

// Round 4
// 95.579 us; speedup vs baseline: 1.3444x; 1.1054x over previous
//
#include <hip/hip_runtime.h>

// Performer causal linear attention — 3-dispatch bf16-MFMA pipeline.
// B=4, S=2048, D=128; chunks of L=32 (256 chunks total, 64/batch).
//  phikv:  phi = scale*exp(W@x) via MFMA (bf16 in, fp32 acc); K-blocks also
//          compute per-chunk KVT[e][d] + N[d] sums (MFMA, bf16 out).
//  prefix: exclusive scan over 64 chunks/batch -> bf16 PM (M^T) + fp32 PN.
//  out:    P=QK^T (masked) ; out = P@V + Q@M ; fp32 denominators.
typedef float v4 __attribute__((ext_vector_type(4)));
typedef short s8v __attribute__((ext_vector_type(8)));   // bf16x8 fragment
typedef float f4v __attribute__((ext_vector_type(4)));   // mfma C/D
typedef unsigned short u16;
typedef u16 us4 __attribute__((ext_vector_type(4)));
typedef u16 us8 __attribute__((ext_vector_type(8)));

// workspace layout (float units).  NOTE: 8192x128 bf16 = 524288 FLOATS.
// (Round-3 bug: phi buffers sized 262144 f -> phiQ/KVT overlapped phiK/phiQ.)
#define OFF_PHIKB 0            // bf16 [8192][128]           (524288 f)
#define OFF_PHIQB 524288       // bf16 [8192][128]           (524288 f)
#define OFF_KVTB  1048576      // bf16 [4][128][64][128]     (2097152 f)
#define OFF_PMB   3145728      // bf16 [4][128][64][128]     (2097152 f)
#define OFF_N32   5242880      // fp32 [4][64][128]          (32768 f)
#define OFF_PN    5275648      // fp32 [4][64][128]          (32768 f)
// total 5308416 floats = 21.2 MB

__device__ inline u16 f2bf(float f) {
  union { float f; unsigned u; } v; v.f = f;
  unsigned r = v.u + 0x7fffu + ((v.u >> 16) & 1u);
  return (u16)(r >> 16);
}
__device__ inline float bf2f(u16 h) {
  union { unsigned u; float f; } v; v.u = ((unsigned)h) << 16; return v.f;
}

// ---------------------------------------------------------------------------
// Kernel 1: fused phi (+ per-chunk KV/N for the K tensor).
// Grid (128, 2): x = 64-row slab, y = 0:K(+kv) / 1:Q.  256 threads, 4 waves.
// ---------------------------------------------------------------------------
__global__ __launch_bounds__(256) void phikv_kernel(
    const float* __restrict__ K, const float* __restrict__ Q,
    const float* __restrict__ V, const float* __restrict__ W,
    u16* __restrict__ phiKb, u16* __restrict__ phiQb,
    u16* __restrict__ KVTb, float* __restrict__ N32) {
  // phase A: Xb[64][136] @ 0, Wb[128][136] @ 8704   (u16 units)
  // phase B: Pb[64][136] @ 0, KdT[128][72] @ 8704, Vt[128][72] @ 17920
  __shared__ __align__(16) u16 smem[27136];
  __shared__ float srowsq[64];
  __shared__ float scl[64];
  u16* Xb = smem;
  u16* Wb = smem + 8704;
  u16* Pb = smem;
  u16* KdT = smem + 8704;
  u16* Vt = smem + 17920;

  const int tid = threadIdx.x;
  const bool isK = (blockIdx.y == 0);
  const float* X = isK ? K : Q;
  u16* outPhi = isK ? phiKb : phiQb;
  const int row0 = blockIdx.x * 64;
  const int wv = tid >> 6;
  const int lane = tid & 63;
  const int q = lane >> 4;
  const int ln = lane & 15;

  // ---- stage X -> bf16 Xb + per-row sumsq (fp32, shuffle-reduced) ----
#pragma unroll
  for (int k = 0; k < 8; k++) {
    int j = tid + k * 256;
    int r = j >> 5;
    int c4 = (j & 31) * 4;
    v4 x = *(const v4*)&X[(size_t)(row0 + r) * 128 + c4];
    us4 xb;
    float p = 0.f;
#pragma unroll
    for (int i = 0; i < 4; i++) { xb[i] = f2bf(x[i]); p += x[i] * x[i]; }
    *(us4*)&Xb[r * 136 + c4] = xb;
    p += __shfl_down(p, 16, 32);
    p += __shfl_down(p, 8, 32);
    p += __shfl_down(p, 4, 32);
    p += __shfl_down(p, 2, 32);
    p += __shfl_down(p, 1, 32);
    if ((tid & 31) == 0) srowsq[r] = p;
  }
  // ---- stage W -> bf16 Wb ----
#pragma unroll
  for (int k = 0; k < 16; k++) {
    int j = tid + k * 256;
    int r = j >> 5;
    int c4 = (j & 31) * 4;
    v4 w = *(const v4*)&W[(size_t)r * 128 + c4];
    us4 wb;
#pragma unroll
    for (int i = 0; i < 4; i++) wb[i] = f2bf(w[i]);
    *(us4*)&Wb[r * 136 + c4] = wb;
  }
  __syncthreads();
  if (tid < 64)
    scl[tid] = 0.08838834764831845f * __expf(-0.5f * sqrtf(srowsq[tid]));

  // ---- phi MFMA: wave = row-tile, 8 col-tiles, K=128 ----
  f4v acc[8];
#pragma unroll
  for (int ct = 0; ct < 8; ct++) acc[ct] = (f4v){0.f, 0.f, 0.f, 0.f};
#pragma unroll
  for (int ks = 0; ks < 4; ks++) {
    s8v a = *(const s8v*)&Xb[(wv * 16 + ln) * 136 + ks * 32 + q * 8];
#pragma unroll
    for (int ct = 0; ct < 8; ct++) {
      s8v bb = *(const s8v*)&Wb[(ct * 16 + ln) * 136 + ks * 32 + q * 8];
      acc[ct] = __builtin_amdgcn_mfma_f32_16x16x32_bf16(a, bb, acc[ct], 0, 0, 0);
    }
  }
  __syncthreads();  // all MFMA reads of Xb/Wb done; scl ready

  // ---- epilogue: phi values -> Pb (row-major) and KdT (transposed) ----
#pragma unroll
  for (int ct = 0; ct < 8; ct++) {
    us4 col;
#pragma unroll
    for (int r = 0; r < 4; r++) {
      int row = wv * 16 + q * 4 + r;
      u16 hv = f2bf(scl[row] * __expf(acc[ct][r]));
      Pb[row * 136 + ct * 16 + ln] = hv;
      col[r] = hv;
    }
    if (isK) *(us4*)&KdT[(ct * 16 + ln) * 72 + wv * 16 + q * 4] = col;
  }
  // ---- stage V transposed (K-blocks) ----
  if (isK) {
#pragma unroll
    for (int k = 0; k < 8; k++) {
      int j = tid + k * 256;
      int s = j >> 5;
      int e4 = (j & 31) * 4;
      v4 vv = *(const v4*)&V[(size_t)(row0 + s) * 128 + e4];
#pragma unroll
      for (int i = 0; i < 4; i++) Vt[(e4 + i) * 72 + s] = f2bf(vv[i]);
    }
  }
  __syncthreads();

  // ---- phi -> global (coalesced us8) ----
#pragma unroll
  for (int k = 0; k < 4; k++) {
    int j = tid + k * 256;
    int r = j >> 4;
    int d8 = (j & 15) * 8;
    *(us8*)&outPhi[(size_t)(row0 + r) * 128 + d8] = *(const us8*)&Pb[r * 136 + d8];
  }
  if (!isK) return;

  const int b = row0 >> 11;
  const int cgB = (row0 >> 5) & 63;  // first of this block's two chunks

  // ---- N sums: thread -> (chunk, d) ----
  {
    int c = tid >> 7;
    int d = tid & 127;
    float ns = 0.f;
#pragma unroll
    for (int s = 0; s < 32; s++) ns += bf2f(KdT[d * 72 + c * 32 + s]);
    N32[(size_t)(b * 64 + cgB + c) * 128 + d] = ns;
  }

  // ---- kv MFMA: KVT[e][d] = sum_s V[s][e]*phiK[s][d], per chunk ----
#pragma unroll
  for (int c = 0; c < 2; c++) {
#pragma unroll
    for (int ei = 0; ei < 2; ei++) {
      const int et = wv * 2 + ei;
      s8v a = *(const s8v*)&Vt[(et * 16 + ln) * 72 + c * 32 + q * 8];
      f4v ac[8];
#pragma unroll
      for (int dt = 0; dt < 8; dt++) ac[dt] = (f4v){0.f, 0.f, 0.f, 0.f};
#pragma unroll
      for (int dt = 0; dt < 8; dt++) {
        s8v bb = *(const s8v*)&KdT[(dt * 16 + ln) * 72 + c * 32 + q * 8];
        ac[dt] = __builtin_amdgcn_mfma_f32_16x16x32_bf16(a, bb, ac[dt], 0, 0, 0);
      }
#pragma unroll
      for (int dt = 0; dt < 8; dt++)
#pragma unroll
        for (int r = 0; r < 4; r++) {
          int e = et * 16 + q * 4 + r;
          int d = dt * 16 + ln;
          KVTb[((size_t)(b * 128 + e) * 64 + (cgB + c)) * 128 + d] =
              f2bf(ac[dt][r]);
        }
    }
  }
}

// ---------------------------------------------------------------------------
// Kernel 2: exclusive prefix over 64 chunks.  Layout [b][e][c][d] (contig).
// Blocks 0..511: (b*128+e) rows of M^T; 512..515: N.
// ---------------------------------------------------------------------------
__global__ __launch_bounds__(128) void prefix_kernel(
    const u16* __restrict__ KVTb, const float* __restrict__ N32,
    u16* __restrict__ PMb, float* __restrict__ PN) {
  const int tid = threadIdx.x;
  const int bid = blockIdx.x;
  if (bid < 512) {
    const size_t base = (size_t)bid * 64 * 128;
    float acc = 0.f;
#pragma unroll 8
    for (int c = 0; c < 64; c++) {
      PMb[base + c * 128 + tid] = f2bf(acc);
      acc += bf2f(KVTb[base + c * 128 + tid]);
    }
  } else {
    const int b = bid - 512;
    float acc = 0.f;
#pragma unroll 8
    for (int c = 0; c < 64; c++) {
      PN[(size_t)(b * 64 + c) * 128 + tid] = acc;
      acc += N32[(size_t)(b * 64 + c) * 128 + tid];
    }
  }
}

// ---------------------------------------------------------------------------
// Kernel 3: per-chunk outputs via MFMA (verified round 2; PM layout updated).
// ---------------------------------------------------------------------------
__global__ __launch_bounds__(256) void out_kernel(
    const u16* __restrict__ phiKb, const u16* __restrict__ phiQb,
    const float* __restrict__ V, const u16* __restrict__ PMb,
    const float* __restrict__ PN, float* __restrict__ out) {
  __shared__ __align__(16) u16 Qs[32][136];
  __shared__ __align__(16) u16 Ms[128][136];   // M^T: Ms[e][d]
  __shared__ __align__(16) u16 KsVt[128 * 40]; // phase1 Ks[32][136]; phase2 Vt[128][40]
  __shared__ __align__(16) u16 Ps[32][40];
  __shared__ float Ns[128];
  __shared__ float rs[32];

  const int tid = threadIdx.x;
  const int b = blockIdx.x >> 6;
  const int c = blockIdx.x & 63;
  const int srow0 = b * 2048 + c * 32;
  const int wave = tid >> 6;
  const int lane = tid & 63;
  const int q = lane >> 4;
  const int ln = lane & 15;

#pragma unroll
  for (int k = 0; k < 2; k++) {
    int j = tid + k * 256;
    int t = j >> 4;
    int d8 = (j & 15) * 8;
    *(us8*)&Qs[t][d8] = *(const us8*)&phiQb[(size_t)(srow0 + t) * 128 + d8];
    *(us8*)&KsVt[t * 136 + d8] =
        *(const us8*)&phiKb[(size_t)(srow0 + t) * 128 + d8];
  }
#pragma unroll
  for (int k = 0; k < 8; k++) {
    int j = tid + k * 256;
    int e = j >> 4;
    int d8 = (j & 15) * 8;
    *(us8*)&Ms[e][d8] =
        *(const us8*)&PMb[((size_t)(b * 128 + e) * 64 + c) * 128 + d8];
  }
  if (tid < 128) Ns[tid] = PN[(size_t)(b * 64 + c) * 128 + tid];
  __syncthreads();

  // ---- phase 1: P = Q.K^T, causal mask ----
  {
    const int tr = wave >> 1, tc = wave & 1;
    f4v acc = {0.f, 0.f, 0.f, 0.f};
#pragma unroll
    for (int ks = 0; ks < 4; ks++) {
      s8v a = *(const s8v*)&Qs[tr * 16 + ln][ks * 32 + q * 8];
      s8v bb = *(const s8v*)&KsVt[(tc * 16 + ln) * 136 + ks * 32 + q * 8];
      acc = __builtin_amdgcn_mfma_f32_16x16x32_bf16(a, bb, acc, 0, 0, 0);
    }
    const int s_g = tc * 16 + ln;
#pragma unroll
    for (int r = 0; r < 4; r++) {
      int t_g = tr * 16 + q * 4 + r;
      Ps[t_g][s_g] = f2bf(s_g <= t_g ? acc[r] : 0.f);
    }
  }
  __syncthreads();

  // ---- stage Vt + denominators ----
#pragma unroll
  for (int k = 0; k < 4; k++) {
    int j = tid + k * 256;
    int s = j & 31;
    int e4 = (j >> 5) * 4;
    v4 vv = *(const v4*)&V[(size_t)(srow0 + s) * 128 + e4];
#pragma unroll
    for (int i = 0; i < 4; i++) KsVt[(e4 + i) * 40 + s] = f2bf(vv[i]);
  }
  {
    const int t = tid >> 3;
    const int p8 = tid & 7;
    float rsl = 0.f;
#pragma unroll
    for (int s = p8; s < 32; s += 8) rsl += bf2f(Ps[t][s]);
#pragma unroll
    for (int d = p8; d < 128; d += 8) rsl += bf2f(Qs[t][d]) * Ns[d];
    rsl += __shfl_down(rsl, 4, 8);
    rsl += __shfl_down(rsl, 2, 8);
    rsl += __shfl_down(rsl, 1, 8);
    if (p8 == 0) rs[t] = rsl;
  }
  __syncthreads();

  // ---- phase 2: out = P@V + Q@M ----
  const int e0 = wave * 32;
  f4v acc2[2][2];
#pragma unroll
  for (int i = 0; i < 2; i++)
#pragma unroll
    for (int j = 0; j < 2; j++) acc2[i][j] = (f4v){0.f, 0.f, 0.f, 0.f};

#pragma unroll
  for (int tr2 = 0; tr2 < 2; tr2++) {
    s8v a_p = *(const s8v*)&Ps[tr2 * 16 + ln][q * 8];
#pragma unroll
    for (int tc2 = 0; tc2 < 2; tc2++) {
      s8v b_v = *(const s8v*)&KsVt[(e0 + tc2 * 16 + ln) * 40 + q * 8];
      acc2[tr2][tc2] =
          __builtin_amdgcn_mfma_f32_16x16x32_bf16(a_p, b_v, acc2[tr2][tc2], 0, 0, 0);
    }
  }
#pragma unroll
  for (int ks = 0; ks < 4; ks++) {
#pragma unroll
    for (int tr2 = 0; tr2 < 2; tr2++) {
      s8v a_q = *(const s8v*)&Qs[tr2 * 16 + ln][ks * 32 + q * 8];
#pragma unroll
      for (int tc2 = 0; tc2 < 2; tc2++) {
        s8v b_m = *(const s8v*)&Ms[e0 + tc2 * 16 + ln][ks * 32 + q * 8];
        acc2[tr2][tc2] =
            __builtin_amdgcn_mfma_f32_16x16x32_bf16(a_q, b_m, acc2[tr2][tc2], 0, 0, 0);
      }
    }
  }

  // ---- epilogue ----
#pragma unroll
  for (int tr2 = 0; tr2 < 2; tr2++) {
#pragma unroll
    for (int r = 0; r < 4; r++) {
      int t_g = tr2 * 16 + q * 4 + r;
      float rv = rs[t_g];
      float den = rv + (rv > 0.f ? 1e-6f : (rv < 0.f ? -1e-6f : 0.f));
      float inv = 1.f / den;
#pragma unroll
      for (int tc2 = 0; tc2 < 2; tc2++) {
        int e_g = e0 + tc2 * 16 + ln;
        out[(size_t)(srow0 + t_g) * 128 + e_g] = acc2[tr2][tc2][r] * inv;
      }
    }
  }
}

// ---------------------------------------------------------------------------
extern "C" void kernel_launch(void* const* d_in, const int* in_sizes, int n_in,
                              void* d_out, int out_size, void* d_ws,
                              size_t ws_size, hipStream_t stream) {
  (void)in_sizes; (void)n_in; (void)out_size; (void)ws_size;
  const float* K = (const float*)d_in[0];
  const float* Q = (const float*)d_in[1];
  const float* V = (const float*)d_in[2];
  const float* W = (const float*)d_in[6];
  float* out = (float*)d_out;
  float* ws = (float*)d_ws;

  u16* phiKb = (u16*)(ws + OFF_PHIKB);
  u16* phiQb = (u16*)(ws + OFF_PHIQB);
  u16* KVTb = (u16*)(ws + OFF_KVTB);
  u16* PMb = (u16*)(ws + OFF_PMB);
  float* N32 = ws + OFF_N32;
  float* PN = ws + OFF_PN;

  phikv_kernel<<<dim3(128, 2), 256, 0, stream>>>(K, Q, V, W, phiKb, phiQb,
                                                 KVTb, N32);
  prefix_kernel<<<516, 128, 0, stream>>>(KVTb, N32, PMb, PN);
  out_kernel<<<256, 256, 0, stream>>>(phiKb, phiQb, V, PMb, PN, out);
}